// Round 14
// baseline (343.158 us; speedup 1.0000x reference)
//
#include <hip/hip_runtime.h>
#include <hip/hip_bf16.h>

typedef __hip_bfloat16 bf16;
typedef __attribute__((ext_vector_type(8))) short short8;
typedef __attribute__((ext_vector_type(8))) __bf16 bf16x8;
typedef __attribute__((ext_vector_type(4))) float f32x4;

#define BN 20736      // 256*81
#define NNODE 81
#define KNB 20

__device__ inline float bf2f(short s) {
  union { unsigned u; float f; } x; x.u = ((unsigned)(unsigned short)s) << 16; return x.f;
}
__device__ inline short f2bf(float f) {
  __hip_bfloat16 h = __float2bfloat16(f);
  return *reinterpret_cast<short*>(&h);
}
__device__ inline bf16x8 ld8(const bf16* p) {
  return __builtin_bit_cast(bf16x8, *(const short8*)p);
}

// ---------- 48-col helpers (fused_in, edge) ----------
__device__ inline void zacc3(f32x4 acc[3]) {
  #pragma unroll
  for (int nt = 0; nt < 3; ++nt) acc[nt] = (f32x4){0.f, 0.f, 0.f, 0.f};
}
__device__ inline void load_w48(const bf16* __restrict__ W, int ldw, int n0, int lr, int lq,
                                bf16x8 wf[3][3]) {
  #pragma unroll
  for (int nt = 0; nt < 3; ++nt)
    #pragma unroll
    for (int ks = 0; ks < 3; ++ks)
      wf[nt][ks] = ld8(&W[(size_t)(n0 + nt * 16 + lr) * ldw + ks * 32 + lq * 8]);
}
__device__ inline void gemm48(const bf16x8 af[3], const bf16x8 wf[3][3], f32x4 acc[3]) {
  #pragma unroll
  for (int ks = 0; ks < 3; ++ks)
    #pragma unroll
    for (int nt = 0; nt < 3; ++nt)
      acc[nt] = __builtin_amdgcn_mfma_f32_16x16x32_bf16(af[ks], wf[nt][ks], acc[nt], 0, 0, 0);
}
__device__ inline void acc_store_cs(float* xw, const f32x4 acc[3], int lr, int lq, int n0) {
  #pragma unroll
  for (int nt = 0; nt < 3; ++nt)
    #pragma unroll
    for (int r = 0; r < 4; ++r)
      xw[(lq * 4 + r) * 100 + n0 + nt * 16 + lr] = acc[nt][r];
}
// ---------- 96-col helpers (wave-private iter) ----------
__device__ inline void zacc6(f32x4 acc[6]) {
  #pragma unroll
  for (int nt = 0; nt < 6; ++nt) acc[nt] = (f32x4){0.f, 0.f, 0.f, 0.f};
}
__device__ inline void gemm96w(const bf16* __restrict__ W, int ldw,
                               const bf16x8 af[3], int lr, int lq, f32x4 acc[6]) {
  #pragma unroll
  for (int nt = 0; nt < 6; ++nt)
    #pragma unroll
    for (int ks = 0; ks < 3; ++ks) {
      bf16x8 wf = ld8(&W[(size_t)(nt * 16 + lr) * ldw + ks * 32 + lq * 8]);
      acc[nt] = __builtin_amdgcn_mfma_f32_16x16x32_bf16(af[ks], wf, acc[nt], 0, 0, 0);
    }
}
__device__ inline void acc_store96(float* xw, const f32x4 acc[6], int lr, int lq) {
  #pragma unroll
  for (int nt = 0; nt < 6; ++nt)
    #pragma unroll
    for (int r = 0; r < 4; ++r)
      xw[(lq * 4 + r) * 100 + nt * 16 + lr] = acc[nt][r];
}
__device__ inline void xbuf_frag(const float* xw, int lr, int lq,
                                 const float* __restrict__ bias, float bscale,
                                 const bf16* residRow, int act,
                                 bf16x8 af[3]) {
  #pragma unroll
  for (int ks = 0; ks < 3; ++ks) {
    const int c0 = ks * 32 + lq * 8;
    float4 x0 = *(const float4*)&xw[lr * 100 + c0];
    float4 x1 = *(const float4*)&xw[lr * 100 + c0 + 4];
    float xv[8] = {x0.x, x0.y, x0.z, x0.w, x1.x, x1.y, x1.z, x1.w};
    if (bias) {
      float4 b0 = *(const float4*)&bias[c0];
      float4 b1 = *(const float4*)&bias[c0 + 4];
      float bv[8] = {b0.x, b0.y, b0.z, b0.w, b1.x, b1.y, b1.z, b1.w};
      #pragma unroll
      for (int j = 0; j < 8; ++j) xv[j] += bscale * bv[j];
    }
    if (residRow) {
      short8 r8 = *(const short8*)&residRow[c0];
      #pragma unroll
      for (int j = 0; j < 8; ++j) xv[j] += bf2f(r8[j]);
    }
    short8 o;
    #pragma unroll
    for (int j = 0; j < 8; ++j) {
      float v = xv[j];
      if (act) v = fmaxf(v, 0.f);
      o[j] = f2bf(v);
    }
    af[ks] = __builtin_bit_cast(bf16x8, o);
  }
}
__device__ inline void store_frag(bf16* dst, int lq, const bf16x8 af[3]) {
  #pragma unroll
  for (int ks = 0; ks < 3; ++ks)
    *(short8*)&dst[ks * 32 + lq * 8] = __builtin_bit_cast(short8, af[ks]);
}

// ================= prologue: convert/build all weights =================
__global__ __launch_bounds__(256) void prep_k(
    const float* in_w1, const float* in_w2, const float* f_w1, const float* f_w2,
    const float* g_w1, const float* g_w2, const float* r_w0, const float* r_w1,
    const float* r_w2, const float* wih, const float* whh, const float* g_w0,
    const float* f_w0, const float* in_w0, const float* f_b0,
    bf16* inw1b, bf16* inw2b, bf16* fw1b, bf16* fw2b,
    bf16* gw1b, bf16* gw2b, bf16* rw0b, bf16* rw1b,
    bf16* rw2b, bf16* wihb, bf16* whhb, bf16* gw0b,
    bf16* wfnb, bf16* w0pb, float* bias_fn)
{
  int idx = blockIdx.x * 256 + threadIdx.x;
  int y = blockIdx.y;
  const float* src = nullptr; bf16* dst = nullptr; int cnt = 0;
  switch (y) {
    case 0:  src = in_w1; dst = inw1b; cnt = 9216;  break;
    case 1:  src = in_w2; dst = inw2b; cnt = 9216;  break;
    case 2:  src = f_w1;  dst = fw1b;  cnt = 9216;  break;
    case 3:  src = f_w2;  dst = fw2b;  cnt = 9216;  break;
    case 4:  src = g_w1;  dst = gw1b;  cnt = 9216;  break;
    case 5:  src = g_w2;  dst = gw2b;  cnt = 9216;  break;
    case 6:  src = r_w0;  dst = rw0b;  cnt = 9216;  break;
    case 7:  src = r_w1;  dst = rw1b;  cnt = 9216;  break;
    case 8:  src = r_w2;  dst = rw2b;  cnt = 864;   break;
    case 9:  src = wih;   dst = wihb;  cnt = 36864; break;
    case 10: src = whh;   dst = whhb;  cnt = 36864; break;
    case 11: src = g_w0;  dst = gw0b;  cnt = 18432; break;
    case 12: {
      if (idx < 18432) {
        int n = idx / 96, k = idx - n * 96;
        float v = (n < 96) ? f_w0[n * 192 + k] : f_w0[(n - 96) * 192 + 96 + k];
        wfnb[idx] = __float2bfloat16(v);
      }
      return;
    }
    case 13: {
      if (idx < 3072) {
        int n = idx >> 5, k = idx & 31;
        w0pb[idx] = __float2bfloat16(k < 16 ? in_w0[n * 16 + k] : 0.f);
      }
      return;
    }
    default: {
      if (idx < 192) bias_fn[idx] = (idx < 96) ? f_b0[idx] : 0.f;
      return;
    }
  }
  if (idx < cnt) dst[idx] = __float2bfloat16(src[idx]);
}

// ================= fused input chain (embed folded in, R13) =================
__global__ __launch_bounds__(256) void fused_in_k(
    const float* __restrict__ embed, const int* __restrict__ grids,
    const bf16* __restrict__ w0pb, const float* __restrict__ in_b0,
    const bf16* __restrict__ inw1b, const float* __restrict__ in_b1,
    const bf16* __restrict__ inw2b, const float* __restrict__ in_b2,
    const bf16* __restrict__ gw0b, const float* __restrict__ g_b0,
    const bf16* __restrict__ wfnb, const float* __restrict__ bias_fn,
    bf16* __restrict__ X, bf16* __restrict__ Xg, bf16* __restrict__ P)
{
  __shared__ float xbuf[2][2][1600];
  const int t = threadIdx.x, w = t >> 6, lane = t & 63, lr = lane & 15, lq = lane >> 4;
  const int mh = w >> 1, ch = w & 1, n0 = ch * 48;
  const int m0 = blockIdx.x * 32 + mh * 16;
  float* x0 = xbuf[0][mh];
  float* x1 = xbuf[1][mh];
  bf16x8 wf[3][3]; f32x4 acc[3]; bf16x8 af[3];

  short8 es = {0, 0, 0, 0, 0, 0, 0, 0};
  if (lq < 2) {
    int gidx = grids[m0 + lr];
    float4 e0 = *(const float4*)&embed[gidx * 16 + lq * 8];
    float4 e1 = *(const float4*)&embed[gidx * 16 + lq * 8 + 4];
    es[0] = f2bf(e0.x); es[1] = f2bf(e0.y); es[2] = f2bf(e0.z); es[3] = f2bf(e0.w);
    es[4] = f2bf(e1.x); es[5] = f2bf(e1.y); es[6] = f2bf(e1.z); es[7] = f2bf(e1.w);
  }
  bf16x8 a0 = __builtin_bit_cast(bf16x8, es);
  #pragma unroll
  for (int nt = 0; nt < 3; ++nt)
    wf[nt][0] = ld8(&w0pb[(size_t)(n0 + nt * 16 + lr) * 32 + lq * 8]);
  zacc3(acc);
  #pragma unroll
  for (int nt = 0; nt < 3; ++nt)
    acc[nt] = __builtin_amdgcn_mfma_f32_16x16x32_bf16(a0, wf[nt][0], acc[nt], 0, 0, 0);
  acc_store_cs(x0, acc, lr, lq, n0);
  __syncthreads();
  xbuf_frag(x0, lr, lq, in_b0, 1.f, nullptr, 1, af);
  load_w48(inw1b, 96, n0, lr, lq, wf); zacc3(acc); gemm48(af, wf, acc);
  acc_store_cs(x1, acc, lr, lq, n0);
  __syncthreads();
  xbuf_frag(x1, lr, lq, in_b1, 1.f, nullptr, 1, af);
  load_w48(inw2b, 96, n0, lr, lq, wf); zacc3(acc); gemm48(af, wf, acc);
  acc_store_cs(x0, acc, lr, lq, n0);
  __syncthreads();
  bf16x8 xf[3];
  xbuf_frag(x0, lr, lq, in_b2, 1.f, nullptr, 0, xf);
  if (ch == 0) store_frag(&X[(size_t)(m0 + lr) * 96], lq, xf);
  load_w48(gw0b, 192, n0, lr, lq, wf); zacc3(acc); gemm48(xf, wf, acc);
  acc_store_cs(x1, acc, lr, lq, n0);
  __syncthreads();
  xbuf_frag(x1, lr, lq, g_b0, 1.f, nullptr, 0, af);
  if (ch == 0) store_frag(&Xg[(size_t)(m0 + lr) * 96], lq, af);
  #pragma unroll
  for (int ph = 0; ph < 2; ++ph) {
    float* xb = ph ? x1 : x0;
    load_w48(wfnb + (size_t)ph * 96 * 96, 96, n0, lr, lq, wf); zacc3(acc); gemm48(xf, wf, acc);
    acc_store_cs(xb, acc, lr, lq, n0);
    __syncthreads();
    xbuf_frag(xb, lr, lq, bias_fn + ph * 96, 1.f, nullptr, 0, af);
    if (ch == 0) store_frag(&P[(size_t)(m0 + lr) * 192 + ph * 96], lq, af);
  }
}

// ===== edge kernel (R13): 4 nodes/block, 128 thr, 20KB LDS -> 8 blocks/CU =====
__global__ __launch_bounds__(128) void edge_k(
    const bf16* __restrict__ P, const bf16* __restrict__ w1bf,
    const float* __restrict__ b1, const int* __restrict__ edges,
    const bf16* __restrict__ fw2b, const float* __restrict__ f_b2,
    bf16* __restrict__ M)
{
  __shared__ short zs[80 * 104];
  __shared__ short sbuf[16 * 104];
  const int t = threadIdx.x;
  const int grp = (blockIdx.x & 7) * 648 + (blockIdx.x >> 3);
  const int w = t >> 6, lane = t & 63, lr = lane & 15, lq = lane >> 4;
  const int n0 = w * 48;

  bf16x8 wf1[3][3];
  #pragma unroll
  for (int nt = 0; nt < 3; ++nt)
    #pragma unroll
    for (int ks = 0; ks < 3; ++ks)
      wf1[nt][ks] = ld8(&w1bf[(size_t)(n0 + nt * 16 + lr) * 96 + ks * 32 + lq * 8]);
  float b1v[3];
  #pragma unroll
  for (int nt = 0; nt < 3; ++nt) b1v[nt] = b1[n0 + nt * 16 + lr];

  for (int i = t; i < 12 * 104; i += 128) sbuf[(4 + i / 104) * 104 + (i % 104)] = 0;
  for (int cc = t; cc < 80 * 12; cc += 128) {
    int row = cc / 12, c8 = cc - row * 12;
    int p = row / 20, j = row - p * 20;
    int gr = grp * 4 + p;
    int b = gr / NNODE, i = gr - b * NNODE;
    int e = edges[i * KNB + j];
    short8 a8 = *(const short8*)&P[(size_t)gr * 192 + c8 * 8];
    short8 n8 = *(const short8*)&P[((size_t)b * NNODE + e) * 192 + 96 + c8 * 8];
    short8 z;
    #pragma unroll
    for (int q = 0; q < 8; ++q)
      z[q] = f2bf(fmaxf(bf2f(a8[q]) + bf2f(n8[q]), 0.f));
    *(short8*)&zs[row * 104 + c8 * 8] = z;
  }
  __syncthreads();

  f32x4 acc[5][3];
  #pragma unroll
  for (int mt = 0; mt < 5; ++mt)
    #pragma unroll
    for (int nt = 0; nt < 3; ++nt) acc[mt][nt] = (f32x4){0.f, 0.f, 0.f, 0.f};
  #pragma unroll
  for (int ks = 0; ks < 3; ++ks) {
    const int koff = ks * 32 + lq * 8;
    #pragma unroll
    for (int mt = 0; mt < 5; ++mt) {
      bf16x8 af = __builtin_bit_cast(bf16x8, *(const short8*)&zs[(mt * 16 + lr) * 104 + koff]);
      #pragma unroll
      for (int nt = 0; nt < 3; ++nt)
        acc[mt][nt] = __builtin_amdgcn_mfma_f32_16x16x32_bf16(af, wf1[nt][ks], acc[mt][nt], 0, 0, 0);
    }
  }

  float nodeacc[4][3];
  #pragma unroll
  for (int pp = 0; pp < 4; ++pp)
    #pragma unroll
    for (int nt = 0; nt < 3; ++nt) nodeacc[pp][nt] = 0.f;
  #pragma unroll
  for (int mt = 0; mt < 5; ++mt)
    #pragma unroll
    for (int nt = 0; nt < 3; ++nt)
      #pragma unroll
      for (int r = 0; r < 4; ++r) {
        int row = mt * 16 + lq * 4 + r;
        int p = row / 20;
        float v = fmaxf(acc[mt][nt][r] + b1v[nt], 0.f);
        #pragma unroll
        for (int pp = 0; pp < 4; ++pp)
          nodeacc[pp][nt] += (p == pp) ? v : 0.f;
      }
  #pragma unroll
  for (int pp = 0; pp < 4; ++pp)
    #pragma unroll
    for (int nt = 0; nt < 3; ++nt) {
      float v = nodeacc[pp][nt];
      v += __shfl_xor(v, 16, 64);
      v += __shfl_xor(v, 32, 64);
      if (lq == 0)
        sbuf[pp * 104 + n0 + nt * 16 + lr] = f2bf(v);
    }
  __syncthreads();

  bf16x8 mwf[3][3];
  #pragma unroll
  for (int nt = 0; nt < 3; ++nt)
    #pragma unroll
    for (int ks = 0; ks < 3; ++ks)
      mwf[nt][ks] = ld8(&fw2b[(size_t)(n0 + nt * 16 + lr) * 96 + ks * 32 + lq * 8]);
  f32x4 macc[3];
  zacc3(macc);
  #pragma unroll
  for (int ks = 0; ks < 3; ++ks) {
    bf16x8 af = __builtin_bit_cast(bf16x8, *(const short8*)&sbuf[lr * 104 + ks * 32 + lq * 8]);
    #pragma unroll
    for (int nt = 0; nt < 3; ++nt)
      macc[nt] = __builtin_amdgcn_mfma_f32_16x16x32_bf16(af, mwf[nt][ks], macc[nt], 0, 0, 0);
  }
  if (lq == 0) {
    #pragma unroll
    for (int nt = 0; nt < 3; ++nt) {
      int col = n0 + nt * 16 + lr;
      float bb = (float)KNB * f_b2[col];
      #pragma unroll
      for (int r = 0; r < 4; ++r)
        M[(size_t)(grp * 4 + r) * 96 + col] = __float2bfloat16(macc[nt][r] + bb);
    }
  }
}

// ===== wave-private fused iteration kernel: 64 thr, 16 rows x 96 cols, ZERO barriers =====
__global__ __launch_bounds__(64) void fused_iter_k(
    const bf16* __restrict__ Min,
    const bf16* __restrict__ gw0b, const bf16* __restrict__ Xg,
    const bf16* __restrict__ gw1b, const float* __restrict__ g_b1,
    const bf16* __restrict__ gw2b, const float* __restrict__ g_b2,
    const bf16* __restrict__ Hin,
    const bf16* __restrict__ wihb, const bf16* __restrict__ whhb,
    const float* __restrict__ bih, const float* __restrict__ bhh,
    float* __restrict__ c, bf16* __restrict__ Hout,
    const bf16* __restrict__ wfnb, const float* __restrict__ bias_fn, bf16* __restrict__ P,
    const bf16* __restrict__ rw0b, const float* __restrict__ r_b0,
    const bf16* __restrict__ rw1b, const float* __restrict__ r_b1,
    const bf16* __restrict__ rw2b, const float* __restrict__ r_b2,
    float* __restrict__ outp, int doP)
{
  __shared__ float xb0[1600], xb1[1600];
  const int t = threadIdx.x, lr = t & 15, lq = t >> 4;
  const int m0 = blockIdx.x * 16;

  bf16x8 af[3];
  f32x4 acc[6];

  // hoisted A-reads
  #pragma unroll
  for (int ks = 0; ks < 3; ++ks)
    af[ks] = ld8(&Min[(size_t)(m0 + lr) * 96 + ks * 32 + lq * 8]);
  bf16x8 hin[3];
  #pragma unroll
  for (int ks = 0; ks < 3; ++ks)
    hin[ks] = ld8(&Hin[(size_t)(m0 + lr) * 96 + ks * 32 + lq * 8]);

  // S1: Min @ g_w0[:,96:]^T
  zacc6(acc); gemm96w(gw0b + 96, 192, af, lr, lq, acc);
  acc_store96(xb0, acc, lr, lq);
  xbuf_frag(xb0, lr, lq, nullptr, 0.f, &Xg[(size_t)(m0 + lr) * 96], 1, af);
  // S2: z1 @ g_w1^T
  zacc6(acc); gemm96w(gw1b, 96, af, lr, lq, acc);
  acc_store96(xb1, acc, lr, lq);
  xbuf_frag(xb1, lr, lq, g_b1, 1.f, nullptr, 1, af);
  // S3: z2 @ g_w2^T
  zacc6(acc); gemm96w(gw2b, 96, af, lr, lq, acc);
  acc_store96(xb0, acc, lr, lq);
  bf16x8 gf[3];
  xbuf_frag(xb0, lr, lq, g_b2, 1.f, nullptr, 0, gf);

  // prefetch c
  float cv[6][4];
  #pragma unroll
  for (int nt = 0; nt < 6; ++nt)
    #pragma unroll
    for (int r = 0; r < 4; ++r)
      cv[nt][r] = c[(size_t)(m0 + lq * 4 + r) * 96 + nt * 16 + lr];

  // LSTM: 4 gates x 96 cols
  f32x4 ga[4][6];
  #pragma unroll
  for (int g4 = 0; g4 < 4; ++g4)
    #pragma unroll
    for (int nt = 0; nt < 6; ++nt) ga[g4][nt] = (f32x4){0.f, 0.f, 0.f, 0.f};
  #pragma unroll
  for (int g4 = 0; g4 < 4; ++g4)
    #pragma unroll
    for (int nt = 0; nt < 6; ++nt) {
      size_t nrow = (size_t)(g4 * 96 + nt * 16 + lr) * 96;
      #pragma unroll
      for (int ks = 0; ks < 3; ++ks) {
        ga[g4][nt] = __builtin_amdgcn_mfma_f32_16x16x32_bf16(
            gf[ks], ld8(&wihb[nrow + ks * 32 + lq * 8]), ga[g4][nt], 0, 0, 0);
        ga[g4][nt] = __builtin_amdgcn_mfma_f32_16x16x32_bf16(
            hin[ks], ld8(&whhb[nrow + ks * 32 + lq * 8]), ga[g4][nt], 0, 0, 0);
      }
    }
  #pragma unroll
  for (int nt = 0; nt < 6; ++nt) {
    int col = nt * 16 + lr;
    float bvi = bih[col] + bhh[col];
    float bvf = bih[96 + col] + bhh[96 + col];
    float bvg = bih[192 + col] + bhh[192 + col];
    float bvo = bih[288 + col] + bhh[288 + col];
    #pragma unroll
    for (int r = 0; r < 4; ++r) {
      int m = m0 + lq * 4 + r;
      size_t idx = (size_t)m * 96 + col;
      float gi = ga[0][nt][r] + bvi;
      float gfv = ga[1][nt][r] + bvf;
      float gg = ga[2][nt][r] + bvg;
      float go = ga[3][nt][r] + bvo;
      float si = 1.f / (1.f + expf(-gi));
      float sf = 1.f / (1.f + expf(-gfv));
      float so = 1.f / (1.f + expf(-go));
      float tg = tanhf(gg);
      float cn = sf * cv[nt][r] + si * tg;
      if (doP) c[idx] = cn;
      xb1[(lq * 4 + r) * 100 + col] = so * tanhf(cn);
    }
  }
  bf16x8 hf[3];
  xbuf_frag(xb1, lr, lq, nullptr, 0.f, nullptr, 0, hf);

  if (doP) {
    // coalesced Hout write from xb1 (program order protects xb1)
    #pragma unroll
    for (int cc = 0; cc < 3; ++cc) {
      int idx = t + cc * 64;
      int row = idx / 12, c8 = idx - row * 12;
      short8 o;
      #pragma unroll
      for (int j = 0; j < 8; ++j) o[j] = f2bf(xb1[row * 100 + c8 * 8 + j]);
      *(short8*)&Hout[(size_t)(m0 + row) * 96 + c8 * 8] = o;
    }
    // P half 0
    zacc6(acc); gemm96w(wfnb, 96, hf, lr, lq, acc);
    #pragma unroll
    for (int nt = 0; nt < 6; ++nt) {
      float bvv = bias_fn[nt * 16 + lr];
      #pragma unroll
      for (int r = 0; r < 4; ++r)
        xb0[(lq * 4 + r) * 100 + nt * 16 + lr] = acc[nt][r] + bvv;
    }
    #pragma unroll
    for (int cc = 0; cc < 3; ++cc) {
      int idx = t + cc * 64;
      int row = idx / 12, c8 = idx - row * 12;
      short8 o;
      #pragma unroll
      for (int j = 0; j < 8; ++j) o[j] = f2bf(xb0[row * 100 + c8 * 8 + j]);
      *(short8*)&P[(size_t)(m0 + row) * 192 + c8 * 8] = o;
    }
    // P half 1
    zacc6(acc); gemm96w(wfnb + 96 * 96, 96, hf, lr, lq, acc);
    #pragma unroll
    for (int nt = 0; nt < 6; ++nt) {
      float bvv = bias_fn[96 + nt * 16 + lr];
      #pragma unroll
      for (int r = 0; r < 4; ++r)
        xb1[(lq * 4 + r) * 100 + nt * 16 + lr] = acc[nt][r] + bvv;
    }
    #pragma unroll
    for (int cc = 0; cc < 3; ++cc) {
      int idx = t + cc * 64;
      int row = idx / 12, c8 = idx - row * 12;
      short8 o;
      #pragma unroll
      for (int j = 0; j < 8; ++j) o[j] = f2bf(xb1[row * 100 + c8 * 8 + j]);
      *(short8*)&P[(size_t)(m0 + row) * 192 + 96 + c8 * 8] = o;
    }
  }

  // r-MLP
  zacc6(acc); gemm96w(rw0b, 96, hf, lr, lq, acc);
  acc_store96(xb0, acc, lr, lq);
  xbuf_frag(xb0, lr, lq, r_b0, 1.f, nullptr, 1, af);
  zacc6(acc); gemm96w(rw1b, 96, af, lr, lq, acc);
  acc_store96(xb1, acc, lr, lq);
  xbuf_frag(xb1, lr, lq, r_b1, 1.f, nullptr, 1, af);
  {
    bf16x8 w9[3];
    #pragma unroll
    for (int ks = 0; ks < 3; ++ks) {
      short8 s = {0, 0, 0, 0, 0, 0, 0, 0};
      if (lr < 9) s = *(const short8*)&rw2b[(size_t)lr * 96 + ks * 32 + lq * 8];
      w9[ks] = __builtin_bit_cast(bf16x8, s);
    }
    f32x4 a9 = (f32x4){0.f, 0.f, 0.f, 0.f};
    #pragma unroll
    for (int ks = 0; ks < 3; ++ks)
      a9 = __builtin_amdgcn_mfma_f32_16x16x32_bf16(af[ks], w9[ks], a9, 0, 0, 0);
    if (lr < 9) {
      float bb = r_b2[lr];
      #pragma unroll
      for (int r = 0; r < 4; ++r)
        outp[(size_t)(m0 + lq * 4 + r) * 9 + lr] = a9[r] + bb;
    }
  }
}

// ================= host side =================
extern "C" void kernel_launch(void* const* d_in, const int* in_sizes, int n_in,
                              void* d_out, int out_size, void* d_ws, size_t ws_size,
                              hipStream_t stream) {
  const float* embed   = (const float*)d_in[0];
  const float* in_w0   = (const float*)d_in[1];
  const float* in_b0   = (const float*)d_in[2];
  const float* in_w1   = (const float*)d_in[3];
  const float* in_b1   = (const float*)d_in[4];
  const float* in_w2   = (const float*)d_in[5];
  const float* in_b2   = (const float*)d_in[6];
  const float* f_w0    = (const float*)d_in[7];
  const float* f_b0    = (const float*)d_in[8];
  const float* f_w1    = (const float*)d_in[9];
  const float* f_b1    = (const float*)d_in[10];
  const float* f_w2    = (const float*)d_in[11];
  const float* f_b2    = (const float*)d_in[12];
  const float* g_w0    = (const float*)d_in[13];
  const float* g_b0    = (const float*)d_in[14];
  const float* g_w1    = (const float*)d_in[15];
  const float* g_b1    = (const float*)d_in[16];
  const float* g_w2    = (const float*)d_in[17];
  const float* g_b2    = (const float*)d_in[18];
  const float* wih     = (const float*)d_in[19];
  const float* whh     = (const float*)d_in[20];
  const float* bih     = (const float*)d_in[21];
  const float* bhh     = (const float*)d_in[22];
  const float* r_w0    = (const float*)d_in[23];
  const float* r_b0    = (const float*)d_in[24];
  const float* r_w1    = (const float*)d_in[25];
  const float* r_b1    = (const float*)d_in[26];
  const float* r_w2    = (const float*)d_in[27];
  const float* r_b2    = (const float*)d_in[28];
  const float* c0      = (const float*)d_in[29];
  const int*   grids   = (const int*)d_in[30];
  const int*   edges   = (const int*)d_in[31];

  float* out = (float*)d_out;
  const int iters = out_size / (BN * 9);   // = 4

  float* c    = (float*)d_ws;                        // BN*96 f32
  bf16* H0    = (bf16*)(c + (size_t)BN * 96);
  bf16* H1    = H0 + (size_t)BN * 96;
  bf16* Xg    = H1 + (size_t)BN * 96;
  bf16* P     = Xg + (size_t)BN * 96;                // BN*192
  bf16* Mb    = P  + (size_t)BN * 192;
  bf16* w0pb  = Mb + (size_t)BN * 96;                // 3072
  bf16* wfnb  = w0pb + 3072;                         // 18432
  bf16* inw1b = wfnb + 18432;
  bf16* inw2b = inw1b + 9216;
  bf16* fw1b  = inw2b + 9216;
  bf16* fw2b  = fw1b + 9216;
  bf16* gw0b  = fw2b + 9216;                         // 18432
  bf16* gw1b  = gw0b + 18432;
  bf16* gw2b  = gw1b + 9216;
  bf16* rw0b  = gw2b + 9216;
  bf16* rw1b  = rw0b + 9216;
  bf16* rw2b  = rw1b + 9216;                         // 864
  bf16* wihb  = rw2b + 864;                          // 36864
  bf16* whhb  = wihb + 36864;
  float* bias_fn = (float*)(whhb + 36864);           // 192 f32

  prep_k<<<dim3(144, 15), 256, 0, stream>>>(
      in_w1, in_w2, f_w1, f_w2, g_w1, g_w2, r_w0, r_w1, r_w2, wih, whh, g_w0,
      f_w0, in_w0, f_b0,
      inw1b, inw2b, fw1b, fw2b, gw1b, gw2b, rw0b, rw1b, rw2b, wihb, whhb, gw0b,
      wfnb, w0pb, bias_fn);
  fused_in_k<<<BN / 32, 256, 0, stream>>>(embed, grids, w0pb, in_b0, inw1b, in_b1,
                                          inw2b, in_b2, gw0b, g_b0, wfnb, bias_fn,
                                          H0, Xg, P);
  hipMemcpyAsync(c, c0, (size_t)BN * 96 * sizeof(float), hipMemcpyDeviceToDevice, stream);

  for (int it = 0; it < iters; ++it) {
    bf16* Hin  = (it & 1) ? H1 : H0;
    bf16* Hout = (it & 1) ? H0 : H1;
    edge_k<<<BN / 4, 128, 0, stream>>>(P, fw1b, f_b1, edges, fw2b, f_b2, Mb);
    fused_iter_k<<<BN / 16, 64, 0, stream>>>(
        Mb, gw0b, Xg, gw1b, g_b1, gw2b, g_b2,
        Hin, wihb, whhb, bih, bhh, c, Hout,
        wfnb, bias_fn, P, rw0b, r_b0, rw1b, r_b1, rw2b, r_b2,
        out + (size_t)it * BN * 9, it < iters - 1 ? 1 : 0);
  }
}

// Round 15
// 316.635 us; speedup vs baseline: 1.0838x; 1.0838x over previous
//
#include <hip/hip_runtime.h>
#include <hip/hip_bf16.h>

typedef __hip_bfloat16 bf16;
typedef __attribute__((ext_vector_type(8))) short short8;
typedef __attribute__((ext_vector_type(8))) __bf16 bf16x8;
typedef __attribute__((ext_vector_type(4))) float f32x4;

#define BN 20736      // 256*81
#define NNODE 81
#define KNB 20

__device__ inline float bf2f(short s) {
  union { unsigned u; float f; } x; x.u = ((unsigned)(unsigned short)s) << 16; return x.f;
}
__device__ inline short f2bf(float f) {
  __hip_bfloat16 h = __float2bfloat16(f);
  return *reinterpret_cast<short*>(&h);
}
__device__ inline bf16x8 ld8(const bf16* p) {
  return __builtin_bit_cast(bf16x8, *(const short8*)p);
}

// ---------- 48-col helpers ----------
__device__ inline void zacc3(f32x4 acc[3]) {
  #pragma unroll
  for (int nt = 0; nt < 3; ++nt) acc[nt] = (f32x4){0.f, 0.f, 0.f, 0.f};
}
__device__ inline void load_w48(const bf16* __restrict__ W, int ldw, int n0, int lr, int lq,
                                bf16x8 wf[3][3]) {
  #pragma unroll
  for (int nt = 0; nt < 3; ++nt)
    #pragma unroll
    for (int ks = 0; ks < 3; ++ks)
      wf[nt][ks] = ld8(&W[(size_t)(n0 + nt * 16 + lr) * ldw + ks * 32 + lq * 8]);
}
__device__ inline void gemm48(const bf16x8 af[3], const bf16x8 wf[3][3], f32x4 acc[3]) {
  #pragma unroll
  for (int ks = 0; ks < 3; ++ks)
    #pragma unroll
    for (int nt = 0; nt < 3; ++nt)
      acc[nt] = __builtin_amdgcn_mfma_f32_16x16x32_bf16(af[ks], wf[nt][ks], acc[nt], 0, 0, 0);
}
__device__ inline void acc_store_cs(float* xw, const f32x4 acc[3], int lr, int lq, int n0) {
  #pragma unroll
  for (int nt = 0; nt < 3; ++nt)
    #pragma unroll
    for (int r = 0; r < 4; ++r)
      xw[(lq * 4 + r) * 100 + n0 + nt * 16 + lr] = acc[nt][r];
}
__device__ inline void xbuf_frag(const float* xw, int lr, int lq,
                                 const float* __restrict__ bias, float bscale,
                                 const bf16* residRow, int act,
                                 bf16x8 af[3]) {
  #pragma unroll
  for (int ks = 0; ks < 3; ++ks) {
    const int c0 = ks * 32 + lq * 8;
    float4 x0 = *(const float4*)&xw[lr * 100 + c0];
    float4 x1 = *(const float4*)&xw[lr * 100 + c0 + 4];
    float xv[8] = {x0.x, x0.y, x0.z, x0.w, x1.x, x1.y, x1.z, x1.w};
    if (bias) {
      float4 b0 = *(const float4*)&bias[c0];
      float4 b1 = *(const float4*)&bias[c0 + 4];
      float bv[8] = {b0.x, b0.y, b0.z, b0.w, b1.x, b1.y, b1.z, b1.w};
      #pragma unroll
      for (int j = 0; j < 8; ++j) xv[j] += bscale * bv[j];
    }
    if (residRow) {
      short8 r8 = *(const short8*)&residRow[c0];
      #pragma unroll
      for (int j = 0; j < 8; ++j) xv[j] += bf2f(r8[j]);
    }
    short8 o;
    #pragma unroll
    for (int j = 0; j < 8; ++j) {
      float v = xv[j];
      if (act) v = fmaxf(v, 0.f);
      o[j] = f2bf(v);
    }
    af[ks] = __builtin_bit_cast(bf16x8, o);
  }
}
__device__ inline void store_frag(bf16* dst, int lq, const bf16x8 af[3]) {
  #pragma unroll
  for (int ks = 0; ks < 3; ++ks)
    *(short8*)&dst[ks * 32 + lq * 8] = __builtin_bit_cast(short8, af[ks]);
}

// ================= prologue 1: convert/build all weights =================
__global__ __launch_bounds__(256) void prep_k(
    const float* in_w1, const float* in_w2, const float* f_w1, const float* f_w2,
    const float* g_w1, const float* g_w2, const float* r_w0, const float* r_w1,
    const float* r_w2, const float* wih, const float* whh, const float* g_w0,
    const float* f_w0, const float* in_w0, const float* f_b0,
    bf16* inw1b, bf16* inw2b, bf16* fw1b, bf16* fw2b,
    bf16* gw1b, bf16* gw2b, bf16* rw0b, bf16* rw1b,
    bf16* rw2b, bf16* wihb, bf16* whhb, bf16* gw0b,
    bf16* wfnb, bf16* w0pb, float* bias_fn)
{
  int idx = blockIdx.x * 256 + threadIdx.x;
  int y = blockIdx.y;
  const float* src = nullptr; bf16* dst = nullptr; int cnt = 0;
  switch (y) {
    case 0:  src = in_w1; dst = inw1b; cnt = 9216;  break;
    case 1:  src = in_w2; dst = inw2b; cnt = 9216;  break;
    case 2:  src = f_w1;  dst = fw1b;  cnt = 9216;  break;
    case 3:  src = f_w2;  dst = fw2b;  cnt = 9216;  break;
    case 4:  src = g_w1;  dst = gw1b;  cnt = 9216;  break;
    case 5:  src = g_w2;  dst = gw2b;  cnt = 9216;  break;
    case 6:  src = r_w0;  dst = rw0b;  cnt = 9216;  break;
    case 7:  src = r_w1;  dst = rw1b;  cnt = 9216;  break;
    case 8:  src = r_w2;  dst = rw2b;  cnt = 864;   break;
    case 9:  src = wih;   dst = wihb;  cnt = 36864; break;
    case 10: src = whh;   dst = whhb;  cnt = 36864; break;
    case 11: src = g_w0;  dst = gw0b;  cnt = 18432; break;
    case 12: {
      if (idx < 18432) {
        int n = idx / 96, k = idx - n * 96;
        float v = (n < 96) ? f_w0[n * 192 + k] : f_w0[(n - 96) * 192 + 96 + k];
        wfnb[idx] = __float2bfloat16(v);
      }
      return;
    }
    case 13: {
      if (idx < 3072) {
        int n = idx >> 5, k = idx & 31;
        w0pb[idx] = __float2bfloat16(k < 16 ? in_w0[n * 16 + k] : 0.f);
      }
      return;
    }
    default: {
      if (idx < 192) bias_fn[idx] = (idx < 96) ? f_b0[idx] : 0.f;
      return;
    }
  }
  if (idx < cnt) dst[idx] = __float2bfloat16(src[idx]);
}

// ============ prologue 2: combined weights (f32 matmuls, rounded once) ============
// W_mc[n][k] = sum_j g_w0[n][96+j] f_w2[j][k];  b_mc[n] = sum_j g_w0[n][96+j]*20*f_b2[j]
// W_gc[m][k] = sum_j wih[m][j] g_w2[j][k];      b_lc[m] = bih[m]+bhh[m]+sum_j wih[m][j] g_b2[j]
__global__ __launch_bounds__(256) void prep2_k(
    const float* __restrict__ g_w0, const float* __restrict__ f_w2,
    const float* __restrict__ f_b2, const float* __restrict__ wih,
    const float* __restrict__ g_w2, const float* __restrict__ g_b2,
    const float* __restrict__ bih, const float* __restrict__ bhh,
    bf16* __restrict__ wmcb, float* __restrict__ b_mc,
    bf16* __restrict__ wgcb, float* __restrict__ b_lc)
{
  int idx = blockIdx.x * 256 + threadIdx.x;
  if (idx < 9216) {
    int n = idx / 96, k = idx - n * 96;
    float s = 0.f;
    for (int j = 0; j < 96; ++j) s += g_w0[n * 192 + 96 + j] * f_w2[j * 96 + k];
    wmcb[idx] = __float2bfloat16(s);
  } else if (idx < 9216 + 36864) {
    int r = idx - 9216;
    int m = r / 96, k = r - m * 96;
    float s = 0.f;
    for (int j = 0; j < 96; ++j) s += wih[m * 96 + j] * g_w2[j * 96 + k];
    wgcb[r] = __float2bfloat16(s);
  } else if (idx < 9216 + 36864 + 96) {
    int n = idx - 9216 - 36864;
    float s = 0.f;
    for (int j = 0; j < 96; ++j) s += g_w0[n * 192 + 96 + j] * 20.f * f_b2[j];
    b_mc[n] = s;
  } else if (idx < 9216 + 36864 + 96 + 384) {
    int m = idx - 9216 - 36864 - 96;
    float s = bih[m] + bhh[m];
    for (int j = 0; j < 96; ++j) s += wih[m * 96 + j] * g_b2[j];
    b_lc[m] = s;
  }
}

// ================= fused input chain (embed folded in, R13) =================
__global__ __launch_bounds__(256) void fused_in_k(
    const float* __restrict__ embed, const int* __restrict__ grids,
    const bf16* __restrict__ w0pb, const float* __restrict__ in_b0,
    const bf16* __restrict__ inw1b, const float* __restrict__ in_b1,
    const bf16* __restrict__ inw2b, const float* __restrict__ in_b2,
    const bf16* __restrict__ gw0b, const float* __restrict__ g_b0,
    const bf16* __restrict__ wfnb, const float* __restrict__ bias_fn,
    bf16* __restrict__ X, bf16* __restrict__ Xg, bf16* __restrict__ P)
{
  __shared__ float xbuf[2][2][1600];
  const int t = threadIdx.x, w = t >> 6, lane = t & 63, lr = lane & 15, lq = lane >> 4;
  const int mh = w >> 1, ch = w & 1, n0 = ch * 48;
  const int m0 = blockIdx.x * 32 + mh * 16;
  float* x0 = xbuf[0][mh];
  float* x1 = xbuf[1][mh];
  bf16x8 wf[3][3]; f32x4 acc[3]; bf16x8 af[3];

  short8 es = {0, 0, 0, 0, 0, 0, 0, 0};
  if (lq < 2) {
    int gidx = grids[m0 + lr];
    float4 e0 = *(const float4*)&embed[gidx * 16 + lq * 8];
    float4 e1 = *(const float4*)&embed[gidx * 16 + lq * 8 + 4];
    es[0] = f2bf(e0.x); es[1] = f2bf(e0.y); es[2] = f2bf(e0.z); es[3] = f2bf(e0.w);
    es[4] = f2bf(e1.x); es[5] = f2bf(e1.y); es[6] = f2bf(e1.z); es[7] = f2bf(e1.w);
  }
  bf16x8 a0 = __builtin_bit_cast(bf16x8, es);
  #pragma unroll
  for (int nt = 0; nt < 3; ++nt)
    wf[nt][0] = ld8(&w0pb[(size_t)(n0 + nt * 16 + lr) * 32 + lq * 8]);
  zacc3(acc);
  #pragma unroll
  for (int nt = 0; nt < 3; ++nt)
    acc[nt] = __builtin_amdgcn_mfma_f32_16x16x32_bf16(a0, wf[nt][0], acc[nt], 0, 0, 0);
  acc_store_cs(x0, acc, lr, lq, n0);
  __syncthreads();
  xbuf_frag(x0, lr, lq, in_b0, 1.f, nullptr, 1, af);
  load_w48(inw1b, 96, n0, lr, lq, wf); zacc3(acc); gemm48(af, wf, acc);
  acc_store_cs(x1, acc, lr, lq, n0);
  __syncthreads();
  xbuf_frag(x1, lr, lq, in_b1, 1.f, nullptr, 1, af);
  load_w48(inw2b, 96, n0, lr, lq, wf); zacc3(acc); gemm48(af, wf, acc);
  acc_store_cs(x0, acc, lr, lq, n0);
  __syncthreads();
  bf16x8 xf[3];
  xbuf_frag(x0, lr, lq, in_b2, 1.f, nullptr, 0, xf);
  if (ch == 0) store_frag(&X[(size_t)(m0 + lr) * 96], lq, xf);
  load_w48(gw0b, 192, n0, lr, lq, wf); zacc3(acc); gemm48(xf, wf, acc);
  acc_store_cs(x1, acc, lr, lq, n0);
  __syncthreads();
  xbuf_frag(x1, lr, lq, g_b0, 1.f, nullptr, 0, af);
  if (ch == 0) store_frag(&Xg[(size_t)(m0 + lr) * 96], lq, af);
  #pragma unroll
  for (int ph = 0; ph < 2; ++ph) {
    float* xb = ph ? x1 : x0;
    load_w48(wfnb + (size_t)ph * 96 * 96, 96, n0, lr, lq, wf); zacc3(acc); gemm48(xf, wf, acc);
    acc_store_cs(xb, acc, lr, lq, n0);
    __syncthreads();
    xbuf_frag(xb, lr, lq, bias_fn + ph * 96, 1.f, nullptr, 0, af);
    if (ch == 0) store_frag(&P[(size_t)(m0 + lr) * 192 + ph * 96], lq, af);
  }
}

// ===== edge kernel: 4 nodes/block, 128 thr, writes S directly (no M tail) =====
__global__ __launch_bounds__(128) void edge_k(
    const bf16* __restrict__ P, const bf16* __restrict__ w1bf,
    const float* __restrict__ b1, const int* __restrict__ edges,
    bf16* __restrict__ S)
{
  __shared__ short zs[80 * 104];
  const int t = threadIdx.x;
  const int grp = (blockIdx.x & 7) * 648 + (blockIdx.x >> 3);
  const int w = t >> 6, lane = t & 63, lr = lane & 15, lq = lane >> 4;
  const int n0 = w * 48;

  bf16x8 wf1[3][3];
  #pragma unroll
  for (int nt = 0; nt < 3; ++nt)
    #pragma unroll
    for (int ks = 0; ks < 3; ++ks)
      wf1[nt][ks] = ld8(&w1bf[(size_t)(n0 + nt * 16 + lr) * 96 + ks * 32 + lq * 8]);
  float b1v[3];
  #pragma unroll
  for (int nt = 0; nt < 3; ++nt) b1v[nt] = b1[n0 + nt * 16 + lr];

  for (int cc = t; cc < 80 * 12; cc += 128) {
    int row = cc / 12, c8 = cc - row * 12;
    int p = row / 20, j = row - p * 20;
    int gr = grp * 4 + p;
    int b = gr / NNODE, i = gr - b * NNODE;
    int e = edges[i * KNB + j];
    short8 a8 = *(const short8*)&P[(size_t)gr * 192 + c8 * 8];
    short8 n8 = *(const short8*)&P[((size_t)b * NNODE + e) * 192 + 96 + c8 * 8];
    short8 z;
    #pragma unroll
    for (int q = 0; q < 8; ++q)
      z[q] = f2bf(fmaxf(bf2f(a8[q]) + bf2f(n8[q]), 0.f));
    *(short8*)&zs[row * 104 + c8 * 8] = z;
  }
  __syncthreads();

  f32x4 acc[5][3];
  #pragma unroll
  for (int mt = 0; mt < 5; ++mt)
    #pragma unroll
    for (int nt = 0; nt < 3; ++nt) acc[mt][nt] = (f32x4){0.f, 0.f, 0.f, 0.f};
  #pragma unroll
  for (int ks = 0; ks < 3; ++ks) {
    const int koff = ks * 32 + lq * 8;
    #pragma unroll
    for (int mt = 0; mt < 5; ++mt) {
      bf16x8 af = __builtin_bit_cast(bf16x8, *(const short8*)&zs[(mt * 16 + lr) * 104 + koff]);
      #pragma unroll
      for (int nt = 0; nt < 3; ++nt)
        acc[mt][nt] = __builtin_amdgcn_mfma_f32_16x16x32_bf16(af, wf1[nt][ks], acc[mt][nt], 0, 0, 0);
    }
  }

  float nodeacc[4][3];
  #pragma unroll
  for (int pp = 0; pp < 4; ++pp)
    #pragma unroll
    for (int nt = 0; nt < 3; ++nt) nodeacc[pp][nt] = 0.f;
  #pragma unroll
  for (int mt = 0; mt < 5; ++mt)
    #pragma unroll
    for (int nt = 0; nt < 3; ++nt)
      #pragma unroll
      for (int r = 0; r < 4; ++r) {
        int row = mt * 16 + lq * 4 + r;
        int p = row / 20;
        float v = fmaxf(acc[mt][nt][r] + b1v[nt], 0.f);
        #pragma unroll
        for (int pp = 0; pp < 4; ++pp)
          nodeacc[pp][nt] += (p == pp) ? v : 0.f;
      }
  #pragma unroll
  for (int pp = 0; pp < 4; ++pp)
    #pragma unroll
    for (int nt = 0; nt < 3; ++nt) {
      float v = nodeacc[pp][nt];
      v += __shfl_xor(v, 16, 64);
      v += __shfl_xor(v, 32, 64);
      if (lq == 0)
        S[(size_t)(grp * 4 + pp) * 96 + n0 + nt * 16 + lr] = __float2bfloat16(v);
    }
}

// ===== fused iteration kernel: S -> z1(W_mc) -> z2 -> gates(W_gc) -> LSTM -> {P, r-MLP} =====
__global__ __launch_bounds__(128) void fused_iter_k(
    const bf16* __restrict__ Sin,
    const bf16* __restrict__ wmcb, const float* __restrict__ b_mc,
    const bf16* __restrict__ Xg,
    const bf16* __restrict__ gw1b, const float* __restrict__ g_b1,
    const bf16* __restrict__ Hin,
    const bf16* __restrict__ wgcb, const bf16* __restrict__ whhb,
    const float* __restrict__ b_lc,
    float* __restrict__ c, bf16* __restrict__ Hout,
    const bf16* __restrict__ wfnb, const float* __restrict__ bias_fn, bf16* __restrict__ P,
    const bf16* __restrict__ rw0b, const float* __restrict__ r_b0,
    const bf16* __restrict__ rw1b, const float* __restrict__ r_b1,
    const bf16* __restrict__ rw2b, const float* __restrict__ r_b2,
    float* __restrict__ outp, int doP)
{
  __shared__ float xb0[1600], xb1[1600];
  const int t = threadIdx.x, w = t >> 6, lane = t & 63, lr = lane & 15, lq = lane >> 4;
  const int n0 = w * 48;
  const int m0 = blockIdx.x * 16;

  bf16x8 wfA[3][3], wfB[3][3], af[3];
  f32x4 acc[3];

  // hoisted global A-reads
  #pragma unroll
  for (int ks = 0; ks < 3; ++ks)
    af[ks] = ld8(&Sin[(size_t)(m0 + lr) * 96 + ks * 32 + lq * 8]);
  bf16x8 hin[3];
  #pragma unroll
  for (int ks = 0; ks < 3; ++ks)
    hin[ks] = ld8(&Hin[(size_t)(m0 + lr) * 96 + ks * 32 + lq * 8]);

  // S1': z1 = relu(S @ W_mc^T + b_mc + Xg)
  load_w48(wmcb, 96, n0, lr, lq, wfA);
  zacc3(acc); gemm48(af, wfA, acc);
  load_w48(gw1b, 96, n0, lr, lq, wfB);           // prefetch S2
  acc_store_cs(xb0, acc, lr, lq, n0);
  __syncthreads();                               // B1
  xbuf_frag(xb0, lr, lq, b_mc, 1.f, &Xg[(size_t)(m0 + lr) * 96], 1, af);
  // S2: z2 = relu(z1 @ g_w1^T + g_b1)
  zacc3(acc); gemm48(af, wfB, acc);
  acc_store_cs(xb1, acc, lr, lq, n0);
  __syncthreads();                               // B2
  bf16x8 zf[3];
  xbuf_frag(xb1, lr, lq, g_b1, 1.f, nullptr, 1, zf);

  // prefetch c (overlaps the 72-MFMA gate block)
  float cv[3][4];
  #pragma unroll
  for (int nt = 0; nt < 3; ++nt)
    #pragma unroll
    for (int r = 0; r < 4; ++r)
      cv[nt][r] = c[(size_t)(m0 + lq * 4 + r) * 96 + n0 + nt * 16 + lr];

  // gates = z2 @ W_gc^T + Hin @ whh^T + b_lc ; 4 gates x this wave's 48 cols
  f32x4 ga[4][3];
  #pragma unroll
  for (int g4 = 0; g4 < 4; ++g4)
    #pragma unroll
    for (int nt = 0; nt < 3; ++nt) ga[g4][nt] = (f32x4){0.f, 0.f, 0.f, 0.f};
  #pragma unroll
  for (int g4 = 0; g4 < 4; ++g4)
    #pragma unroll
    for (int nt = 0; nt < 3; ++nt) {
      size_t nrow = (size_t)(g4 * 96 + n0 + nt * 16 + lr) * 96;
      #pragma unroll
      for (int ks = 0; ks < 3; ++ks) {
        ga[g4][nt] = __builtin_amdgcn_mfma_f32_16x16x32_bf16(
            zf[ks], ld8(&wgcb[nrow + ks * 32 + lq * 8]), ga[g4][nt], 0, 0, 0);
        ga[g4][nt] = __builtin_amdgcn_mfma_f32_16x16x32_bf16(
            hin[ks], ld8(&whhb[nrow + ks * 32 + lq * 8]), ga[g4][nt], 0, 0, 0);
      }
    }
  #pragma unroll
  for (int nt = 0; nt < 3; ++nt) {
    int col = n0 + nt * 16 + lr;
    float bvi = b_lc[col];
    float bvf = b_lc[96 + col];
    float bvg = b_lc[192 + col];
    float bvo = b_lc[288 + col];
    #pragma unroll
    for (int r = 0; r < 4; ++r) {
      int m = m0 + lq * 4 + r;
      size_t idx = (size_t)m * 96 + col;
      float gi = ga[0][nt][r] + bvi;
      float gfv = ga[1][nt][r] + bvf;
      float gg = ga[2][nt][r] + bvg;
      float go = ga[3][nt][r] + bvo;
      float si = 1.f / (1.f + expf(-gi));
      float sf = 1.f / (1.f + expf(-gfv));
      float so = 1.f / (1.f + expf(-go));
      float tg = tanhf(gg);
      float cn = sf * cv[nt][r] + si * tg;
      if (doP) c[idx] = cn;
      xb1[(lq * 4 + r) * 100 + col] = so * tanhf(cn);
    }
  }
  __syncthreads();                               // B3
  bf16x8 hf[3];
  xbuf_frag(xb1, lr, lq, nullptr, 0.f, nullptr, 0, hf);

  if (doP) {
    for (int cc = t; cc < 192; cc += 128) {
      int row = cc / 12, c8 = cc - row * 12;
      short8 o;
      #pragma unroll
      for (int j = 0; j < 8; ++j) o[j] = f2bf(xb1[row * 100 + c8 * 8 + j]);
      *(short8*)&Hout[(size_t)(m0 + row) * 96 + c8 * 8] = o;
    }
    load_w48(wfnb, 96, n0, lr, lq, wfA);
    zacc3(acc); gemm48(hf, wfA, acc);
    load_w48(wfnb + 96 * 96, 96, n0, lr, lq, wfB);
    #pragma unroll
    for (int nt = 0; nt < 3; ++nt) {
      float bvv = bias_fn[n0 + nt * 16 + lr];
      #pragma unroll
      for (int r = 0; r < 4; ++r)
        xb0[(lq * 4 + r) * 100 + n0 + nt * 16 + lr] = acc[nt][r] + bvv;
    }
    __syncthreads();                             // B4
    for (int cc = t; cc < 192; cc += 128) {
      int row = cc / 12, c8 = cc - row * 12;
      short8 o;
      #pragma unroll
      for (int j = 0; j < 8; ++j) o[j] = f2bf(xb0[row * 100 + c8 * 8 + j]);
      *(short8*)&P[(size_t)(m0 + row) * 192 + c8 * 8] = o;
    }
    zacc3(acc); gemm48(hf, wfB, acc);
    #pragma unroll
    for (int nt = 0; nt < 3; ++nt) {
      float bvv = bias_fn[96 + n0 + nt * 16 + lr];
      #pragma unroll
      for (int r = 0; r < 4; ++r)
        xb1[(lq * 4 + r) * 100 + n0 + nt * 16 + lr] = acc[nt][r] + bvv;
    }
    __syncthreads();                             // B5
    for (int cc = t; cc < 192; cc += 128) {
      int row = cc / 12, c8 = cc - row * 12;
      short8 o;
      #pragma unroll
      for (int j = 0; j < 8; ++j) o[j] = f2bf(xb1[row * 100 + c8 * 8 + j]);
      *(short8*)&P[(size_t)(m0 + row) * 192 + 96 + c8 * 8] = o;
    }
  }

  // r-MLP
  load_w48(rw0b, 96, n0, lr, lq, wfA);
  zacc3(acc); gemm48(hf, wfA, acc);
  load_w48(rw1b, 96, n0, lr, lq, wfB);
  __syncthreads();                               // B6
  acc_store_cs(xb0, acc, lr, lq, n0);
  __syncthreads();                               // B7
  xbuf_frag(xb0, lr, lq, r_b0, 1.f, nullptr, 1, af);
  zacc3(acc); gemm48(af, wfB, acc);
  acc_store_cs(xb1, acc, lr, lq, n0);
  __syncthreads();                               // B8
  xbuf_frag(xb1, lr, lq, r_b1, 1.f, nullptr, 1, af);
  if (w == 0) {
    bf16x8 w9[3];
    #pragma unroll
    for (int ks = 0; ks < 3; ++ks) {
      short8 s = {0, 0, 0, 0, 0, 0, 0, 0};
      if (lr < 9) s = *(const short8*)&rw2b[(size_t)lr * 96 + ks * 32 + lq * 8];
      w9[ks] = __builtin_bit_cast(bf16x8, s);
    }
    f32x4 a9 = (f32x4){0.f, 0.f, 0.f, 0.f};
    #pragma unroll
    for (int ks = 0; ks < 3; ++ks)
      a9 = __builtin_amdgcn_mfma_f32_16x16x32_bf16(af[ks], w9[ks], a9, 0, 0, 0);
    if (lr < 9) {
      float bb = r_b2[lr];
      #pragma unroll
      for (int r = 0; r < 4; ++r)
        outp[(size_t)(m0 + lq * 4 + r) * 9 + lr] = a9[r] + bb;
    }
  }
}

// ================= host side =================
extern "C" void kernel_launch(void* const* d_in, const int* in_sizes, int n_in,
                              void* d_out, int out_size, void* d_ws, size_t ws_size,
                              hipStream_t stream) {
  const float* embed   = (const float*)d_in[0];
  const float* in_w0   = (const float*)d_in[1];
  const float* in_b0   = (const float*)d_in[2];
  const float* in_w1   = (const float*)d_in[3];
  const float* in_b1   = (const float*)d_in[4];
  const float* in_w2   = (const float*)d_in[5];
  const float* in_b2   = (const float*)d_in[6];
  const float* f_w0    = (const float*)d_in[7];
  const float* f_b0    = (const float*)d_in[8];
  const float* f_w1    = (const float*)d_in[9];
  const float* f_b1    = (const float*)d_in[10];
  const float* f_w2    = (const float*)d_in[11];
  const float* f_b2    = (const float*)d_in[12];
  const float* g_w0    = (const float*)d_in[13];
  const float* g_b0    = (const float*)d_in[14];
  const float* g_w1    = (const float*)d_in[15];
  const float* g_b1    = (const float*)d_in[16];
  const float* g_w2    = (const float*)d_in[17];
  const float* g_b2    = (const float*)d_in[18];
  const float* wih     = (const float*)d_in[19];
  const float* whh     = (const float*)d_in[20];
  const float* bih     = (const float*)d_in[21];
  const float* bhh     = (const float*)d_in[22];
  const float* r_w0    = (const float*)d_in[23];
  const float* r_b0    = (const float*)d_in[24];
  const float* r_w1    = (const float*)d_in[25];
  const float* r_b1    = (const float*)d_in[26];
  const float* r_w2    = (const float*)d_in[27];
  const float* r_b2    = (const float*)d_in[28];
  const float* c0      = (const float*)d_in[29];
  const int*   grids   = (const int*)d_in[30];
  const int*   edges   = (const int*)d_in[31];

  float* out = (float*)d_out;
  const int iters = out_size / (BN * 9);   // = 4

  float* c    = (float*)d_ws;                        // BN*96 f32
  bf16* H0    = (bf16*)(c + (size_t)BN * 96);
  bf16* H1    = H0 + (size_t)BN * 96;
  bf16* Xg    = H1 + (size_t)BN * 96;
  bf16* P     = Xg + (size_t)BN * 96;                // BN*192
  bf16* Sb    = P  + (size_t)BN * 192;               // BN*96
  bf16* w0pb  = Sb + (size_t)BN * 96;                // 3072
  bf16* wfnb  = w0pb + 3072;                         // 18432
  bf16* inw1b = wfnb + 18432;
  bf16* inw2b = inw1b + 9216;
  bf16* fw1b  = inw2b + 9216;
  bf16* fw2b  = fw1b + 9216;
  bf16* gw0b  = fw2b + 9216;                         // 18432
  bf16* gw1b  = gw0b + 18432;
  bf16* gw2b  = gw1b + 9216;
  bf16* rw0b  = gw2b + 9216;
  bf16* rw1b  = rw0b + 9216;
  bf16* rw2b  = rw1b + 9216;                         // 864
  bf16* wihb  = rw2b + 864;                          // 36864
  bf16* whhb  = wihb + 36864;
  bf16* wmcb  = whhb + 36864;                        // 9216
  bf16* wgcb  = wmcb + 9216;                         // 36864
  float* bias_fn = (float*)(wgcb + 36864);           // 192 f32
  float* b_mc    = bias_fn + 192;                    // 96 f32
  float* b_lc    = b_mc + 96;                        // 384 f32

  prep_k<<<dim3(144, 15), 256, 0, stream>>>(
      in_w1, in_w2, f_w1, f_w2, g_w1, g_w2, r_w0, r_w1, r_w2, wih, whh, g_w0,
      f_w0, in_w0, f_b0,
      inw1b, inw2b, fw1b, fw2b, gw1b, gw2b, rw0b, rw1b, rw2b, wihb, whhb, gw0b,
      wfnb, w0pb, bias_fn);
  prep2_k<<<(9216 + 36864 + 480 + 255) / 256, 256, 0, stream>>>(
      g_w0, f_w2, f_b2, wih, g_w2, g_b2, bih, bhh, wmcb, b_mc, wgcb, b_lc);
  fused_in_k<<<BN / 32, 256, 0, stream>>>(embed, grids, w0pb, in_b0, inw1b, in_b1,
                                          inw2b, in_b2, gw0b, g_b0, wfnb, bias_fn,
                                          H0, Xg, P);
  hipMemcpyAsync(c, c0, (size_t)BN * 96 * sizeof(float), hipMemcpyDeviceToDevice, stream);

  for (int it = 0; it < iters; ++it) {
    bf16* Hin  = (it & 1) ? H1 : H0;
    bf16* Hout = (it & 1) ? H0 : H1;
    edge_k<<<BN / 4, 128, 0, stream>>>(P, fw1b, f_b1, edges, Sb);
    fused_iter_k<<<BN / 16, 128, 0, stream>>>(
        Sb, wmcb, b_mc, Xg, gw1b, g_b1,
        Hin, wgcb, whhb, b_lc, c, Hout,
        wfnb, bias_fn, P, rw0b, r_b0, rw1b, r_b1, rw2b, r_b2,
        out + (size_t)it * BN * 9, it < iters - 1 ? 1 : 0);
  }
}

// Round 16
// 314.770 us; speedup vs baseline: 1.0902x; 1.0059x over previous
//
#include <hip/hip_runtime.h>
#include <hip/hip_bf16.h>

typedef __hip_bfloat16 bf16;
typedef __attribute__((ext_vector_type(8))) short short8;
typedef __attribute__((ext_vector_type(8))) __bf16 bf16x8;
typedef __attribute__((ext_vector_type(4))) float f32x4;

#define BN 20736      // 256*81
#define NNODE 81
#define KNB 20

__device__ inline float bf2f(short s) {
  union { unsigned u; float f; } x; x.u = ((unsigned)(unsigned short)s) << 16; return x.f;
}
__device__ inline short f2bf(float f) {
  __hip_bfloat16 h = __float2bfloat16(f);
  return *reinterpret_cast<short*>(&h);
}
__device__ inline bf16x8 ld8(const bf16* p) {
  return __builtin_bit_cast(bf16x8, *(const short8*)p);
}

// ---------- 48-col helpers ----------
__device__ inline void zacc3(f32x4 acc[3]) {
  #pragma unroll
  for (int nt = 0; nt < 3; ++nt) acc[nt] = (f32x4){0.f, 0.f, 0.f, 0.f};
}
__device__ inline void load_w48(const bf16* __restrict__ W, int ldw, int n0, int lr, int lq,
                                bf16x8 wf[3][3]) {
  #pragma unroll
  for (int nt = 0; nt < 3; ++nt)
    #pragma unroll
    for (int ks = 0; ks < 3; ++ks)
      wf[nt][ks] = ld8(&W[(size_t)(n0 + nt * 16 + lr) * ldw + ks * 32 + lq * 8]);
}
__device__ inline void gemm48(const bf16x8 af[3], const bf16x8 wf[3][3], f32x4 acc[3]) {
  #pragma unroll
  for (int ks = 0; ks < 3; ++ks)
    #pragma unroll
    for (int nt = 0; nt < 3; ++nt)
      acc[nt] = __builtin_amdgcn_mfma_f32_16x16x32_bf16(af[ks], wf[nt][ks], acc[nt], 0, 0, 0);
}
__device__ inline void acc_store_cs(float* xw, const f32x4 acc[3], int lr, int lq, int n0) {
  #pragma unroll
  for (int nt = 0; nt < 3; ++nt)
    #pragma unroll
    for (int r = 0; r < 4; ++r)
      xw[(lq * 4 + r) * 100 + n0 + nt * 16 + lr] = acc[nt][r];
}
__device__ inline void xbuf_frag(const float* xw, int lr, int lq,
                                 const float* __restrict__ bias, float bscale,
                                 const bf16* residRow, int act,
                                 bf16x8 af[3]) {
  #pragma unroll
  for (int ks = 0; ks < 3; ++ks) {
    const int c0 = ks * 32 + lq * 8;
    float4 x0 = *(const float4*)&xw[lr * 100 + c0];
    float4 x1 = *(const float4*)&xw[lr * 100 + c0 + 4];
    float xv[8] = {x0.x, x0.y, x0.z, x0.w, x1.x, x1.y, x1.z, x1.w};
    if (bias) {
      float4 b0 = *(const float4*)&bias[c0];
      float4 b1 = *(const float4*)&bias[c0 + 4];
      float bv[8] = {b0.x, b0.y, b0.z, b0.w, b1.x, b1.y, b1.z, b1.w};
      #pragma unroll
      for (int j = 0; j < 8; ++j) xv[j] += bscale * bv[j];
    }
    if (residRow) {
      short8 r8 = *(const short8*)&residRow[c0];
      #pragma unroll
      for (int j = 0; j < 8; ++j) xv[j] += bf2f(r8[j]);
    }
    short8 o;
    #pragma unroll
    for (int j = 0; j < 8; ++j) {
      float v = xv[j];
      if (act) v = fmaxf(v, 0.f);
      o[j] = f2bf(v);
    }
    af[ks] = __builtin_bit_cast(bf16x8, o);
  }
}
__device__ inline void store_frag(bf16* dst, int lq, const bf16x8 af[3]) {
  #pragma unroll
  for (int ks = 0; ks < 3; ++ks)
    *(short8*)&dst[ks * 32 + lq * 8] = __builtin_bit_cast(short8, af[ks]);
}

// ================= prologue 1: convert/build all weights =================
__global__ __launch_bounds__(256) void prep_k(
    const float* in_w1, const float* in_w2, const float* f_w1, const float* f_w2,
    const float* g_w1, const float* g_w2, const float* r_w0, const float* r_w1,
    const float* r_w2, const float* wih, const float* whh, const float* g_w0,
    const float* f_w0, const float* in_w0, const float* f_b0,
    bf16* inw1b, bf16* inw2b, bf16* fw1b, bf16* fw2b,
    bf16* gw1b, bf16* gw2b, bf16* rw0b, bf16* rw1b,
    bf16* rw2b, bf16* wihb, bf16* whhb, bf16* gw0b,
    bf16* wfnb, bf16* w0pb, float* bias_fn)
{
  int idx = blockIdx.x * 256 + threadIdx.x;
  int y = blockIdx.y;
  const float* src = nullptr; bf16* dst = nullptr; int cnt = 0;
  switch (y) {
    case 0:  src = in_w1; dst = inw1b; cnt = 9216;  break;
    case 1:  src = in_w2; dst = inw2b; cnt = 9216;  break;
    case 2:  src = f_w1;  dst = fw1b;  cnt = 9216;  break;
    case 3:  src = f_w2;  dst = fw2b;  cnt = 9216;  break;
    case 4:  src = g_w1;  dst = gw1b;  cnt = 9216;  break;
    case 5:  src = g_w2;  dst = gw2b;  cnt = 9216;  break;
    case 6:  src = r_w0;  dst = rw0b;  cnt = 9216;  break;
    case 7:  src = r_w1;  dst = rw1b;  cnt = 9216;  break;
    case 8:  src = r_w2;  dst = rw2b;  cnt = 864;   break;
    case 9:  src = wih;   dst = wihb;  cnt = 36864; break;
    case 10: src = whh;   dst = whhb;  cnt = 36864; break;
    case 11: src = g_w0;  dst = gw0b;  cnt = 18432; break;
    case 12: {
      if (idx < 18432) {
        int n = idx / 96, k = idx - n * 96;
        float v = (n < 96) ? f_w0[n * 192 + k] : f_w0[(n - 96) * 192 + 96 + k];
        wfnb[idx] = __float2bfloat16(v);
      }
      return;
    }
    case 13: {
      if (idx < 3072) {
        int n = idx >> 5, k = idx & 31;
        w0pb[idx] = __float2bfloat16(k < 16 ? in_w0[n * 16 + k] : 0.f);
      }
      return;
    }
    default: {
      if (idx < 192) bias_fn[idx] = (idx < 96) ? f_b0[idx] : 0.f;
      return;
    }
  }
  if (idx < cnt) dst[idx] = __float2bfloat16(src[idx]);
}

// ============ prologue 2: combined weights (f32 matmuls, rounded once) ============
__global__ __launch_bounds__(256) void prep2_k(
    const float* __restrict__ g_w0, const float* __restrict__ f_w2,
    const float* __restrict__ f_b2, const float* __restrict__ wih,
    const float* __restrict__ g_w2, const float* __restrict__ g_b2,
    const float* __restrict__ bih, const float* __restrict__ bhh,
    bf16* __restrict__ wmcb, float* __restrict__ b_mc,
    bf16* __restrict__ wgcb, float* __restrict__ b_lc)
{
  int idx = blockIdx.x * 256 + threadIdx.x;
  if (idx < 9216) {
    int n = idx / 96, k = idx - n * 96;
    float s = 0.f;
    for (int j = 0; j < 96; ++j) s += g_w0[n * 192 + 96 + j] * f_w2[j * 96 + k];
    wmcb[idx] = __float2bfloat16(s);
  } else if (idx < 9216 + 36864) {
    int r = idx - 9216;
    int m = r / 96, k = r - m * 96;
    float s = 0.f;
    for (int j = 0; j < 96; ++j) s += wih[m * 96 + j] * g_w2[j * 96 + k];
    wgcb[r] = __float2bfloat16(s);
  } else if (idx < 9216 + 36864 + 96) {
    int n = idx - 9216 - 36864;
    float s = 0.f;
    for (int j = 0; j < 96; ++j) s += g_w0[n * 192 + 96 + j] * 20.f * f_b2[j];
    b_mc[n] = s;
  } else if (idx < 9216 + 36864 + 96 + 384) {
    int m = idx - 9216 - 36864 - 96;
    float s = bih[m] + bhh[m];
    for (int j = 0; j < 96; ++j) s += wih[m * 96 + j] * g_b2[j];
    b_lc[m] = s;
  }
}

// ================= fused input chain (embed folded in, R13) =================
__global__ __launch_bounds__(256) void fused_in_k(
    const float* __restrict__ embed, const int* __restrict__ grids,
    const bf16* __restrict__ w0pb, const float* __restrict__ in_b0,
    const bf16* __restrict__ inw1b, const float* __restrict__ in_b1,
    const bf16* __restrict__ inw2b, const float* __restrict__ in_b2,
    const bf16* __restrict__ gw0b, const float* __restrict__ g_b0,
    const bf16* __restrict__ wfnb, const float* __restrict__ bias_fn,
    bf16* __restrict__ X, bf16* __restrict__ Xg, bf16* __restrict__ P)
{
  __shared__ float xbuf[2][2][1600];
  const int t = threadIdx.x, w = t >> 6, lane = t & 63, lr = lane & 15, lq = lane >> 4;
  const int mh = w >> 1, ch = w & 1, n0 = ch * 48;
  const int m0 = blockIdx.x * 32 + mh * 16;
  float* x0 = xbuf[0][mh];
  float* x1 = xbuf[1][mh];
  bf16x8 wf[3][3]; f32x4 acc[3]; bf16x8 af[3];

  short8 es = {0, 0, 0, 0, 0, 0, 0, 0};
  if (lq < 2) {
    int gidx = grids[m0 + lr];
    float4 e0 = *(const float4*)&embed[gidx * 16 + lq * 8];
    float4 e1 = *(const float4*)&embed[gidx * 16 + lq * 8 + 4];
    es[0] = f2bf(e0.x); es[1] = f2bf(e0.y); es[2] = f2bf(e0.z); es[3] = f2bf(e0.w);
    es[4] = f2bf(e1.x); es[5] = f2bf(e1.y); es[6] = f2bf(e1.z); es[7] = f2bf(e1.w);
  }
  bf16x8 a0 = __builtin_bit_cast(bf16x8, es);
  #pragma unroll
  for (int nt = 0; nt < 3; ++nt)
    wf[nt][0] = ld8(&w0pb[(size_t)(n0 + nt * 16 + lr) * 32 + lq * 8]);
  zacc3(acc);
  #pragma unroll
  for (int nt = 0; nt < 3; ++nt)
    acc[nt] = __builtin_amdgcn_mfma_f32_16x16x32_bf16(a0, wf[nt][0], acc[nt], 0, 0, 0);
  acc_store_cs(x0, acc, lr, lq, n0);
  __syncthreads();
  xbuf_frag(x0, lr, lq, in_b0, 1.f, nullptr, 1, af);
  load_w48(inw1b, 96, n0, lr, lq, wf); zacc3(acc); gemm48(af, wf, acc);
  acc_store_cs(x1, acc, lr, lq, n0);
  __syncthreads();
  xbuf_frag(x1, lr, lq, in_b1, 1.f, nullptr, 1, af);
  load_w48(inw2b, 96, n0, lr, lq, wf); zacc3(acc); gemm48(af, wf, acc);
  acc_store_cs(x0, acc, lr, lq, n0);
  __syncthreads();
  bf16x8 xf[3];
  xbuf_frag(x0, lr, lq, in_b2, 1.f, nullptr, 0, xf);
  if (ch == 0) store_frag(&X[(size_t)(m0 + lr) * 96], lq, xf);
  load_w48(gw0b, 192, n0, lr, lq, wf); zacc3(acc); gemm48(xf, wf, acc);
  acc_store_cs(x1, acc, lr, lq, n0);
  __syncthreads();
  xbuf_frag(x1, lr, lq, g_b0, 1.f, nullptr, 0, af);
  if (ch == 0) store_frag(&Xg[(size_t)(m0 + lr) * 96], lq, af);
  #pragma unroll
  for (int ph = 0; ph < 2; ++ph) {
    float* xb = ph ? x1 : x0;
    load_w48(wfnb + (size_t)ph * 96 * 96, 96, n0, lr, lq, wf); zacc3(acc); gemm48(xf, wf, acc);
    acc_store_cs(xb, acc, lr, lq, n0);
    __syncthreads();
    xbuf_frag(xb, lr, lq, bias_fn + ph * 96, 1.f, nullptr, 0, af);
    if (ch == 0) store_frag(&P[(size_t)(m0 + lr) * 192 + ph * 96], lq, af);
  }
}

// ===== edge kernel (R15): 4 nodes/block, 128 thr, writes S directly =====
__global__ __launch_bounds__(128) void edge_k(
    const bf16* __restrict__ P, const bf16* __restrict__ w1bf,
    const float* __restrict__ b1, const int* __restrict__ edges,
    bf16* __restrict__ S)
{
  __shared__ short zs[80 * 104];
  const int t = threadIdx.x;
  const int grp = (blockIdx.x & 7) * 648 + (blockIdx.x >> 3);
  const int w = t >> 6, lane = t & 63, lr = lane & 15, lq = lane >> 4;
  const int n0 = w * 48;

  bf16x8 wf1[3][3];
  #pragma unroll
  for (int nt = 0; nt < 3; ++nt)
    #pragma unroll
    for (int ks = 0; ks < 3; ++ks)
      wf1[nt][ks] = ld8(&w1bf[(size_t)(n0 + nt * 16 + lr) * 96 + ks * 32 + lq * 8]);
  float b1v[3];
  #pragma unroll
  for (int nt = 0; nt < 3; ++nt) b1v[nt] = b1[n0 + nt * 16 + lr];

  for (int cc = t; cc < 80 * 12; cc += 128) {
    int row = cc / 12, c8 = cc - row * 12;
    int p = row / 20, j = row - p * 20;
    int gr = grp * 4 + p;
    int b = gr / NNODE, i = gr - b * NNODE;
    int e = edges[i * KNB + j];
    short8 a8 = *(const short8*)&P[(size_t)gr * 192 + c8 * 8];
    short8 n8 = *(const short8*)&P[((size_t)b * NNODE + e) * 192 + 96 + c8 * 8];
    short8 z;
    #pragma unroll
    for (int q = 0; q < 8; ++q)
      z[q] = f2bf(fmaxf(bf2f(a8[q]) + bf2f(n8[q]), 0.f));
    *(short8*)&zs[row * 104 + c8 * 8] = z;
  }
  __syncthreads();

  f32x4 acc[5][3];
  #pragma unroll
  for (int mt = 0; mt < 5; ++mt)
    #pragma unroll
    for (int nt = 0; nt < 3; ++nt) acc[mt][nt] = (f32x4){0.f, 0.f, 0.f, 0.f};
  #pragma unroll
  for (int ks = 0; ks < 3; ++ks) {
    const int koff = ks * 32 + lq * 8;
    #pragma unroll
    for (int mt = 0; mt < 5; ++mt) {
      bf16x8 af = __builtin_bit_cast(bf16x8, *(const short8*)&zs[(mt * 16 + lr) * 104 + koff]);
      #pragma unroll
      for (int nt = 0; nt < 3; ++nt)
        acc[mt][nt] = __builtin_amdgcn_mfma_f32_16x16x32_bf16(af, wf1[nt][ks], acc[mt][nt], 0, 0, 0);
    }
  }

  float nodeacc[4][3];
  #pragma unroll
  for (int pp = 0; pp < 4; ++pp)
    #pragma unroll
    for (int nt = 0; nt < 3; ++nt) nodeacc[pp][nt] = 0.f;
  #pragma unroll
  for (int mt = 0; mt < 5; ++mt)
    #pragma unroll
    for (int nt = 0; nt < 3; ++nt)
      #pragma unroll
      for (int r = 0; r < 4; ++r) {
        int row = mt * 16 + lq * 4 + r;
        int p = row / 20;
        float v = fmaxf(acc[mt][nt][r] + b1v[nt], 0.f);
        #pragma unroll
        for (int pp = 0; pp < 4; ++pp)
          nodeacc[pp][nt] += (p == pp) ? v : 0.f;
      }
  #pragma unroll
  for (int pp = 0; pp < 4; ++pp)
    #pragma unroll
    for (int nt = 0; nt < 3; ++nt) {
      float v = nodeacc[pp][nt];
      v += __shfl_xor(v, 16, 64);
      v += __shfl_xor(v, 32, 64);
      if (lq == 0)
        S[(size_t)(grp * 4 + pp) * 96 + n0 + nt * 16 + lr] = __float2bfloat16(v);
    }
}

// ===== fused iteration kernel: direct stores, 5 barriers =====
__global__ __launch_bounds__(128) void fused_iter_k(
    const bf16* __restrict__ Sin,
    const bf16* __restrict__ wmcb, const float* __restrict__ b_mc,
    const bf16* __restrict__ Xg,
    const bf16* __restrict__ gw1b, const float* __restrict__ g_b1,
    const bf16* __restrict__ Hin,
    const bf16* __restrict__ wgcb, const bf16* __restrict__ whhb,
    const float* __restrict__ b_lc,
    float* __restrict__ c, bf16* __restrict__ Hout,
    const bf16* __restrict__ wfnb, const float* __restrict__ bias_fn, bf16* __restrict__ P,
    const bf16* __restrict__ rw0b, const float* __restrict__ r_b0,
    const bf16* __restrict__ rw1b, const float* __restrict__ r_b1,
    const bf16* __restrict__ rw2b, const float* __restrict__ r_b2,
    float* __restrict__ outp, int doP)
{
  __shared__ float xb0[1600], xb1[1600];
  const int t = threadIdx.x, w = t >> 6, lane = t & 63, lr = lane & 15, lq = lane >> 4;
  const int n0 = w * 48;
  const int m0 = blockIdx.x * 16;

  bf16x8 wfA[3][3], wfB[3][3], af[3];
  f32x4 acc[3];

  // hoisted global A-reads
  #pragma unroll
  for (int ks = 0; ks < 3; ++ks)
    af[ks] = ld8(&Sin[(size_t)(m0 + lr) * 96 + ks * 32 + lq * 8]);
  bf16x8 hin[3];
  #pragma unroll
  for (int ks = 0; ks < 3; ++ks)
    hin[ks] = ld8(&Hin[(size_t)(m0 + lr) * 96 + ks * 32 + lq * 8]);

  // S1': z1 = relu(S @ W_mc^T + b_mc + Xg)
  load_w48(wmcb, 96, n0, lr, lq, wfA);
  zacc3(acc); gemm48(af, wfA, acc);
  load_w48(gw1b, 96, n0, lr, lq, wfB);           // prefetch S2
  acc_store_cs(xb0, acc, lr, lq, n0);
  __syncthreads();                               // B1
  xbuf_frag(xb0, lr, lq, b_mc, 1.f, &Xg[(size_t)(m0 + lr) * 96], 1, af);
  // S2: z2 = relu(z1 @ g_w1^T + g_b1)
  zacc3(acc); gemm48(af, wfB, acc);
  acc_store_cs(xb1, acc, lr, lq, n0);
  // prefetch c (overlaps barrier + gate block)
  float cv[3][4];
  #pragma unroll
  for (int nt = 0; nt < 3; ++nt)
    #pragma unroll
    for (int r = 0; r < 4; ++r)
      cv[nt][r] = c[(size_t)(m0 + lq * 4 + r) * 96 + n0 + nt * 16 + lr];
  __syncthreads();                               // B2
  bf16x8 zf[3];
  xbuf_frag(xb1, lr, lq, g_b1, 1.f, nullptr, 1, zf);

  // gates = z2 @ W_gc^T + Hin @ whh^T + b_lc
  f32x4 ga[4][3];
  #pragma unroll
  for (int g4 = 0; g4 < 4; ++g4)
    #pragma unroll
    for (int nt = 0; nt < 3; ++nt) ga[g4][nt] = (f32x4){0.f, 0.f, 0.f, 0.f};
  #pragma unroll
  for (int g4 = 0; g4 < 4; ++g4)
    #pragma unroll
    for (int nt = 0; nt < 3; ++nt) {
      size_t nrow = (size_t)(g4 * 96 + n0 + nt * 16 + lr) * 96;
      #pragma unroll
      for (int ks = 0; ks < 3; ++ks) {
        ga[g4][nt] = __builtin_amdgcn_mfma_f32_16x16x32_bf16(
            zf[ks], ld8(&wgcb[nrow + ks * 32 + lq * 8]), ga[g4][nt], 0, 0, 0);
        ga[g4][nt] = __builtin_amdgcn_mfma_f32_16x16x32_bf16(
            hin[ks], ld8(&whhb[nrow + ks * 32 + lq * 8]), ga[g4][nt], 0, 0, 0);
      }
    }
  // LSTM epilogue: store c + Hout DIRECTLY (32B segments), h -> xb0
  #pragma unroll
  for (int nt = 0; nt < 3; ++nt) {
    int col = n0 + nt * 16 + lr;
    float bvi = b_lc[col];
    float bvf = b_lc[96 + col];
    float bvg = b_lc[192 + col];
    float bvo = b_lc[288 + col];
    #pragma unroll
    for (int r = 0; r < 4; ++r) {
      int m = m0 + lq * 4 + r;
      size_t idx = (size_t)m * 96 + col;
      float gi = ga[0][nt][r] + bvi;
      float gfv = ga[1][nt][r] + bvf;
      float gg = ga[2][nt][r] + bvg;
      float go = ga[3][nt][r] + bvo;
      float si = 1.f / (1.f + expf(-gi));
      float sf = 1.f / (1.f + expf(-gfv));
      float so = 1.f / (1.f + expf(-go));
      float tg = tanhf(gg);
      float cn = sf * cv[nt][r] + si * tg;
      float ho = so * tanhf(cn);
      if (doP) {
        c[idx] = cn;
        Hout[idx] = __float2bfloat16(ho);
      }
      xb0[(lq * 4 + r) * 100 + col] = ho;        // WAR on xb0 protected by B2
    }
  }
  __syncthreads();                               // B3
  bf16x8 hf[3];
  xbuf_frag(xb0, lr, lq, nullptr, 0.f, nullptr, 0, hf);

  if (doP) {
    // P half 0: GEMM -> direct store
    load_w48(wfnb, 96, n0, lr, lq, wfA);
    zacc3(acc); gemm48(hf, wfA, acc);
    load_w48(wfnb + 96 * 96, 96, n0, lr, lq, wfB);   // prefetch P1
    #pragma unroll
    for (int nt = 0; nt < 3; ++nt) {
      int col = n0 + nt * 16 + lr;
      float bvv = bias_fn[col];
      #pragma unroll
      for (int r = 0; r < 4; ++r)
        P[(size_t)(m0 + lq * 4 + r) * 192 + col] = __float2bfloat16(acc[nt][r] + bvv);
    }
    // P half 1
    zacc3(acc); gemm48(hf, wfB, acc);
    #pragma unroll
    for (int nt = 0; nt < 3; ++nt) {
      int col = n0 + nt * 16 + lr;
      float bvv = bias_fn[96 + col];
      #pragma unroll
      for (int r = 0; r < 4; ++r)
        P[(size_t)(m0 + lq * 4 + r) * 192 + 96 + col] = __float2bfloat16(acc[nt][r] + bvv);
    }
  }

  // r-MLP
  load_w48(rw0b, 96, n0, lr, lq, wfA);
  zacc3(acc); gemm48(hf, wfA, acc);
  load_w48(rw1b, 96, n0, lr, lq, wfB);
  acc_store_cs(xb1, acc, lr, lq, n0);            // WAR on xb1 protected by B3
  __syncthreads();                               // B4
  xbuf_frag(xb1, lr, lq, r_b0, 1.f, nullptr, 1, af);
  zacc3(acc); gemm48(af, wfB, acc);
  acc_store_cs(xb0, acc, lr, lq, n0);            // WAR on xb0 (hf reads) protected by B4
  __syncthreads();                               // B5
  xbuf_frag(xb0, lr, lq, r_b1, 1.f, nullptr, 1, af);
  if (w == 0) {
    bf16x8 w9[3];
    #pragma unroll
    for (int ks = 0; ks < 3; ++ks) {
      short8 s = {0, 0, 0, 0, 0, 0, 0, 0};
      if (lr < 9) s = *(const short8*)&rw2b[(size_t)lr * 96 + ks * 32 + lq * 8];
      w9[ks] = __builtin_bit_cast(bf16x8, s);
    }
    f32x4 a9 = (f32x4){0.f, 0.f, 0.f, 0.f};
    #pragma unroll
    for (int ks = 0; ks < 3; ++ks)
      a9 = __builtin_amdgcn_mfma_f32_16x16x32_bf16(af[ks], w9[ks], a9, 0, 0, 0);
    if (lr < 9) {
      float bb = r_b2[lr];
      #pragma unroll
      for (int r = 0; r < 4; ++r)
        outp[(size_t)(m0 + lq * 4 + r) * 9 + lr] = a9[r] + bb;
    }
  }
}

// ================= host side =================
extern "C" void kernel_launch(void* const* d_in, const int* in_sizes, int n_in,
                              void* d_out, int out_size, void* d_ws, size_t ws_size,
                              hipStream_t stream) {
  const float* embed   = (const float*)d_in[0];
  const float* in_w0   = (const float*)d_in[1];
  const float* in_b0   = (const float*)d_in[2];
  const float* in_w1   = (const float*)d_in[3];
  const float* in_b1   = (const float*)d_in[4];
  const float* in_w2   = (const float*)d_in[5];
  const float* in_b2   = (const float*)d_in[6];
  const float* f_w0    = (const float*)d_in[7];
  const float* f_b0    = (const float*)d_in[8];
  const float* f_w1    = (const float*)d_in[9];
  const float* f_b1    = (const float*)d_in[10];
  const float* f_w2    = (const float*)d_in[11];
  const float* f_b2    = (const float*)d_in[12];
  const float* g_w0    = (const float*)d_in[13];
  const float* g_b0    = (const float*)d_in[14];
  const float* g_w1    = (const float*)d_in[15];
  const float* g_b1    = (const float*)d_in[16];
  const float* g_w2    = (const float*)d_in[17];
  const float* g_b2    = (const float*)d_in[18];
  const float* wih     = (const float*)d_in[19];
  const float* whh     = (const float*)d_in[20];
  const float* bih     = (const float*)d_in[21];
  const float* bhh     = (const float*)d_in[22];
  const float* r_w0    = (const float*)d_in[23];
  const float* r_b0    = (const float*)d_in[24];
  const float* r_w1    = (const float*)d_in[25];
  const float* r_b1    = (const float*)d_in[26];
  const float* r_w2    = (const float*)d_in[27];
  const float* r_b2    = (const float*)d_in[28];
  const float* c0      = (const float*)d_in[29];
  const int*   grids   = (const int*)d_in[30];
  const int*   edges   = (const int*)d_in[31];

  float* out = (float*)d_out;
  const int iters = out_size / (BN * 9);   // = 4

  float* c    = (float*)d_ws;                        // BN*96 f32
  bf16* H0    = (bf16*)(c + (size_t)BN * 96);
  bf16* H1    = H0 + (size_t)BN * 96;
  bf16* Xg    = H1 + (size_t)BN * 96;
  bf16* P     = Xg + (size_t)BN * 96;                // BN*192
  bf16* Sb    = P  + (size_t)BN * 192;               // BN*96
  bf16* w0pb  = Sb + (size_t)BN * 96;                // 3072
  bf16* wfnb  = w0pb + 3072;                         // 18432
  bf16* inw1b = wfnb + 18432;
  bf16* inw2b = inw1b + 9216;
  bf16* fw1b  = inw2b + 9216;
  bf16* fw2b  = fw1b + 9216;
  bf16* gw0b  = fw2b + 9216;                         // 18432
  bf16* gw1b  = gw0b + 18432;
  bf16* gw2b  = gw1b + 9216;
  bf16* rw0b  = gw2b + 9216;
  bf16* rw1b  = rw0b + 9216;
  bf16* rw2b  = rw1b + 9216;                         // 864
  bf16* wihb  = rw2b + 864;                          // 36864
  bf16* whhb  = wihb + 36864;
  bf16* wmcb  = whhb + 36864;                        // 9216
  bf16* wgcb  = wmcb + 9216;                         // 36864
  float* bias_fn = (float*)(wgcb + 36864);           // 192 f32
  float* b_mc    = bias_fn + 192;                    // 96 f32
  float* b_lc    = b_mc + 96;                        // 384 f32

  prep_k<<<dim3(144, 15), 256, 0, stream>>>(
      in_w1, in_w2, f_w1, f_w2, g_w1, g_w2, r_w0, r_w1, r_w2, wih, whh, g_w0,
      f_w0, in_w0, f_b0,
      inw1b, inw2b, fw1b, fw2b, gw1b, gw2b, rw0b, rw1b, rw2b, wihb, whhb, gw0b,
      wfnb, w0pb, bias_fn);
  prep2_k<<<(9216 + 36864 + 480 + 255) / 256, 256, 0, stream>>>(
      g_w0, f_w2, f_b2, wih, g_w2, g_b2, bih, bhh, wmcb, b_mc, wgcb, b_lc);
  fused_in_k<<<BN / 32, 256, 0, stream>>>(embed, grids, w0pb, in_b0, inw1b, in_b1,
                                          inw2b, in_b2, gw0b, g_b0, wfnb, bias_fn,
                                          H0, Xg, P);
  hipMemcpyAsync(c, c0, (size_t)BN * 96 * sizeof(float), hipMemcpyDeviceToDevice, stream);

  for (int it = 0; it < iters; ++it) {
    bf16* Hin  = (it & 1) ? H1 : H0;
    bf16* Hout = (it & 1) ? H0 : H1;
    edge_k<<<BN / 4, 128, 0, stream>>>(P, fw1b, f_b1, edges, Sb);
    fused_iter_k<<<BN / 16, 128, 0, stream>>>(
        Sb, wmcb, b_mc, Xg, gw1b, g_b1,
        Hin, wgcb, whhb, b_lc, c, Hout,
        wfnb, bias_fn, P, rw0b, r_b0, rw1b, r_b1, rw2b, r_b2,
        out + (size_t)it * BN * 9, it < iters - 1 ? 1 : 0);
  }
}